// Round 5
// baseline (467.780 us; speedup 1.0000x reference)
//
#include <hip/hip_runtime.h>
#include <math.h>

#define NN 16384
#define NE 65536
#define HH 128

// ---- constants matching the reference exactly (double, folded to f32) ----
constexpr double D_START = 0.011108996538242306;   // exp(-4.5)
constexpr double D_STEP  = (1.0 - D_START) / 31.0;
constexpr float  F_ALPHA = (float)(5.0/4.5);
constexpr double D_BB    = (2.0/32.0)*(1.0 - D_START);
constexpr float  F_BETA  = (float)(1.0/(D_BB*D_BB));
constexpr float  F_PIC   = (float)(M_PI/4.5);

// fallback scratch pool (used if ws_size too small). ~205 MB needed.
#define POOL_BYTES (224u*1024u*1024u)
__device__ __align__(256) static char g_pool[POOL_BYTES];

typedef __attribute__((ext_vector_type(8))) short bf16x8;
typedef __attribute__((ext_vector_type(4))) float f32x4;

__device__ __forceinline__ float wred64(float x){
  #pragma unroll
  for (int o=32;o;o>>=1) x += __shfl_xor(x, o, 64);
  return x;
}
__device__ __forceinline__ float siluf(float x){
  return x * (1.0f/(1.0f + expf(-x)));
}
__device__ __forceinline__ short f2bf(float x){
  unsigned u = __float_as_uint(x);
  unsigned r = (u + 0x7fffu + ((u>>16)&1u)) >> 16;
  return (short)r;
}
__device__ __forceinline__ float bf2f(short h){
  return __uint_as_float(((unsigned)(unsigned short)h)<<16);
}
__device__ __forceinline__ void split_bf(float x, short& h, short& l){
  h = f2bf(x);
  l = f2bf(x - bf2f(h));
}

// Pk layout (shorts): idx = (n>>4)*40960 + (h>>5)*10240 + (n&15)*640
//                         + ((h>>3)&3)*160 + p*16 + hl*8 + (h&7)
// -> per (node, 32-h chunk, oct) a lane's 10 planes hi/lo are 320 contiguous bytes.

// ---------------- PZ/QZ precompute: PZ[a][h] = emb_w[a]·emb2_w[h, :128] + b[h]
__global__ __launch_bounds__(128) void k_prez(const float* __restrict__ emb_w,
    const float* __restrict__ emb2_w, const float* __restrict__ emb2_b,
    float* __restrict__ PZ, float* __restrict__ QZ){
  __shared__ float erow[128];
  int a = blockIdx.x, h = threadIdx.x;
  erow[h] = emb_w[a*128 + h];
  __syncthreads();
  float p = 0.f, q = 0.f;
  #pragma unroll 8
  for (int k=0;k<128;++k){
    float e = erow[k];
    p += e * emb2_w[h*256 + k];
    q += e * emb2_w[h*256 + 128 + k];
  }
  PZ[a*128 + h] = p + emb2_b[h];
  QZ[a*128 + h] = q;
}

// ---------------- convert weight matrices to bf16 hi/lo (incl. dp1/2/3 concat)
__global__ __launch_bounds__(256) void k_cvtw(
    const float* __restrict__ ls0, const float* __restrict__ ls1,
    const float* __restrict__ lin, const float* __restrict__ lt0,
    const float* __restrict__ lt1, const float* __restrict__ lt2,
    const float* __restrict__ dp1, const float* __restrict__ dp2,
    const float* __restrict__ dp3,
    short* __restrict__ ls0h, short* __restrict__ ls0l,
    short* __restrict__ ls1h, short* __restrict__ ls1l,
    short* __restrict__ linh, short* __restrict__ linl,
    short* __restrict__ lt0h, short* __restrict__ lt0l,
    short* __restrict__ lt1h, short* __restrict__ lt1l,
    short* __restrict__ lt2h, short* __restrict__ lt2l,
    short* __restrict__ dwh, short* __restrict__ dwl){
  int tid = blockIdx.x*256 + threadIdx.x;   // 241664 total
  const float* s; short *dh, *dl; int i;
  if      (tid < 32768)  { s=ls0; dh=ls0h; dl=ls0l; i=tid; }
  else if (tid < 131072) { s=ls1; dh=ls1h; dl=ls1l; i=tid-32768; }
  else if (tid < 180224) { s=lin; dh=linh; dl=linl; i=tid-131072; }
  else if (tid < 196608) { s=lt0; dh=lt0h; dl=lt0l; i=tid-180224; }
  else if (tid < 212992) { s=lt1; dh=lt1h; dl=lt1l; i=tid-196608; }
  else if (tid < 229376) { s=lt2; dh=lt2h; dl=lt2l; i=tid-212992; }
  else {
    int j = tid - 229376;       // 0..12287, [g*4096 + idx]
    int g = j >> 12, idx = j & 4095;
    s = (g==0)?dp1:((g==1)?dp2:dp3);
    dh=dwh; dl=dwl; i=idx;
    short h,l; split_bf(s[i], h, l);
    dh[j] = h; dl[j] = l;
    return;
  }
  short h,l; split_bf(s[i], h, l);
  dh[i] = h; dl[i] = l;
}

// ---------------- per-edge: distance, cutoff, RBF(bf16 hi/lo), normalized vec; histogram
__global__ __launch_bounds__(256) void k_edge(const int* __restrict__ ei,
    const float* __restrict__ pos, const int* __restrict__ z,
    int* __restrict__ counts, int* __restrict__ esrc, int* __restrict__ ezs,
    int* __restrict__ ezd, float* __restrict__ ev,
    short* __restrict__ atth, short* __restrict__ attl){
  int e = blockIdx.x*256 + threadIdx.x;
  if (e >= NE) return;
  int s = ei[e];
  int t = ei[NE + e];
  float dx = pos[3*s+0] - pos[3*t+0];
  float dy = pos[3*s+1] - pos[3*t+1];
  float dz = pos[3*s+2] - pos[3*t+2];
  float d = sqrtf(dx*dx + dy*dy + dz*dz);
  if (d < 4.5f){
    atomicAdd(&counts[s], 1);
    esrc[e] = s;
    ezs[e] = z[s];
    ezd[e] = z[t];
    float denom = (s==t) ? 1.0f : d;
    ev[4*e+0] = dx/denom;
    ev[4*e+1] = dy/denom;
    ev[4*e+2] = dz/denom;
    float cut = 0.5f*(cosf(d*F_PIC) + 1.0f);
    ev[4*e+3] = cut;
    float q = expf(-F_ALPHA*d);
    #pragma unroll
    for (int r=0;r<32;++r){
      float m = (float)(D_START + r*D_STEP);
      float u = q - m;
      float a = cut * expf(-F_BETA*u*u);
      short hh, ll; split_bf(a, hh, ll);
      atth[32*e + r] = hh;
      attl[32*e + r] = ll;
    }
  } else {
    esrc[e] = -1;
  }
}

// ---------------- exclusive scan of 16384 counts (single block)
__global__ __launch_bounds__(1024) void k_scan(const int* __restrict__ counts,
    int* __restrict__ offsets, int* __restrict__ cursor){
  __shared__ int part[1024];
  int t = threadIdx.x;
  int loc[16];
  int s = 0;
  #pragma unroll
  for (int i=0;i<16;++i){ loc[i] = counts[t*16+i]; s += loc[i]; }
  part[t] = s;
  __syncthreads();
  for (int o=1;o<1024;o<<=1){
    int add = (t>=o) ? part[t-o] : 0;
    __syncthreads();
    part[t] += add;
    __syncthreads();
  }
  int excl = (t==0) ? 0 : part[t-1];
  #pragma unroll
  for (int i=0;i<16;++i){
    offsets[t*16+i] = excl;
    cursor[t*16+i] = excl;
    excl += loc[i];
  }
  if (t==1023) offsets[NN] = excl;
}

// ---------------- scatter passing edges into CSR order
__global__ __launch_bounds__(256) void k_scatter(const int* __restrict__ esrc,
    int* __restrict__ cursor, int* __restrict__ elist){
  int e = blockIdx.x*256 + threadIdx.x;
  if (e >= NE) return;
  int s = esrc[e];
  if (s < 0) return;
  int p = atomicAdd(&cursor[s], 1);
  elist[p] = e;
}

// ---------------- per-edge RBF projection via MFMA: D[g][j][h] = att[j]·dpg^T + bg
__global__ __launch_bounds__(256) void k_dstage(const int* __restrict__ offsets,
    const int* __restrict__ elist,
    const short* __restrict__ atth, const short* __restrict__ attl,
    const short* __restrict__ dwh, const short* __restrict__ dwl,
    const float* __restrict__ db1, const float* __restrict__ db2,
    const float* __restrict__ db3,
    float* __restrict__ D1, float* __restrict__ D2, float* __restrict__ D3){
  int nedge = offsets[NN];
  int lane = threadIdx.x & 63;
  int w = threadIdx.x >> 6;
  int m0 = blockIdx.x*64 + w*16;
  if (m0 >= nedge) return;
  int col16 = lane & 15, quad = lane >> 4;
  int arow = m0 + col16;
  int ar = (arow < nedge) ? arow : (nedge-1);
  int e = elist[ar];
  bf16x8 ah = *(const bf16x8*)(atth + (size_t)e*32 + quad*8);
  bf16x8 al = *(const bf16x8*)(attl + (size_t)e*32 + quad*8);
  f32x4 acc[3][8];
  #pragma unroll
  for (int g=0;g<3;++g)
    #pragma unroll
    for (int nt=0;nt<8;++nt) acc[g][nt] = (f32x4){0.f,0.f,0.f,0.f};
  #pragma unroll
  for (int g=0;g<3;++g){
    #pragma unroll
    for (int nt=0;nt<8;++nt){
      int n = nt*16 + col16;
      bf16x8 wh = *(const bf16x8*)(dwh + (g*4096) + n*32 + quad*8);
      bf16x8 wl = *(const bf16x8*)(dwl + (g*4096) + n*32 + quad*8);
      acc[g][nt] = __builtin_amdgcn_mfma_f32_16x16x32_bf16(ah, wh, acc[g][nt], 0,0,0);
      acc[g][nt] = __builtin_amdgcn_mfma_f32_16x16x32_bf16(ah, wl, acc[g][nt], 0,0,0);
      acc[g][nt] = __builtin_amdgcn_mfma_f32_16x16x32_bf16(al, wh, acc[g][nt], 0,0,0);
    }
  }
  const float* bias[3] = {db1, db2, db3};
  float* Dp[3] = {D1, D2, D3};
  #pragma unroll
  for (int g=0;g<3;++g){
    #pragma unroll
    for (int nt=0;nt<8;++nt){
      int n = nt*16 + col16;
      float bb = bias[g][n];
      #pragma unroll
      for (int r=0;r<4;++r){
        int m = m0 + quad*4 + r;   // < NE always
        Dp[g][(size_t)m*128 + n] = acc[g][nt][r] + bb;
      }
    }
  }
}

// ---------------- per-node accumulation of I/A/S planes + fused layernorm(tensor_norm)
// 256 threads = 2 nodes (thread = h); writes Pk in mix-native layout + tnh/tnl
__global__ __launch_bounds__(256) void k_accum2(
    const int* __restrict__ offsets, const int* __restrict__ elist,
    const int* __restrict__ ezs, const int* __restrict__ ezd,
    const float* __restrict__ ev,
    const float* __restrict__ D1, const float* __restrict__ D2,
    const float* __restrict__ D3,
    const float* __restrict__ PZ, const float* __restrict__ QZ,
    const float* __restrict__ gam, const float* __restrict__ bet,
    short* __restrict__ Pk,
    short* __restrict__ tnh, short* __restrict__ tnl){
  __shared__ float red1[4], red2[4];
  int t = threadIdx.x;
  int nl = t >> 7, h = t & 127, wave = t >> 6;
  int n = blockIdx.x*2 + nl;
  int e0 = offsets[n], e1 = offsets[n+1];
  float pv[10];
  #pragma unroll
  for (int i=0;i<10;++i) pv[i]=0.f;
  for (int j=e0; j<e1; ++j){
    int e = elist[j];
    float vx = ev[4*e+0], vy = ev[4*e+1], vz = ev[4*e+2], cut = ev[4*e+3];
    int zs = ezs[e], zd = ezd[e];
    float C = cut * (PZ[zs*128 + h] + QZ[zd*128 + h]);
    float d1 = D1[(size_t)j*128 + h];
    float d2 = D2[(size_t)j*128 + h];
    float d3 = D3[(size_t)j*128 + h];
    float w = d1*C;  pv[0] += w;
    float wa = d2*C; pv[1] += wa*vx; pv[2] += wa*vy; pv[3] += wa*vz;
    float ws = d3*C;
    float t3v = (vx*vx + vy*vy + vz*vz)*(1.0f/3.0f);
    pv[4] += ws*(vx*vx - t3v);
    pv[5] += ws*(vy*vy - t3v);
    pv[6] += ws*(vz*vz - t3v);
    pv[7] += ws*(vx*vy);
    pv[8] += ws*(vx*vz);
    pv[9] += ws*(vy*vz);
  }
  // write Pk: base for this (n, h)
  size_t pb = (size_t)(n>>4)*40960 + (size_t)(h>>5)*10240 + (size_t)(n&15)*640
            + (size_t)((h>>3)&3)*160 + (h&7);
  #pragma unroll
  for (int p=0;p<10;++p){
    short hh, ll; split_bf(pv[p], hh, ll);
    Pk[pb + p*16]     = hh;
    Pk[pb + p*16 + 8] = ll;
  }
  float tn = 3.f*pv[0]*pv[0] + 2.f*(pv[1]*pv[1]+pv[2]*pv[2]+pv[3]*pv[3])
           + (pv[4]*pv[4]+pv[5]*pv[5]+pv[6]*pv[6])
           + 2.f*(pv[7]*pv[7]+pv[8]*pv[8]+pv[9]*pv[9]);
  float sm = wred64(tn);
  if ((t&63)==0) red1[wave] = sm;
  __syncthreads();
  float mean = (red1[nl*2]+red1[nl*2+1])*(1.0f/128.0f);
  float dv = tn - mean;
  float sq = wred64(dv*dv);
  if ((t&63)==0) red2[wave] = sq;
  __syncthreads();
  float var = (red2[nl*2]+red2[nl*2+1])*(1.0f/128.0f);
  float val = dv*(1.0f/sqrtf(var + 1e-5f))*gam[h] + bet[h];
  short hh, ll; split_bf(val, hh, ll);
  size_t idx = (size_t)n*128 + h;
  tnh[idx] = hh; tnl[idx] = ll;
}

// ---------------- split-bf16 MFMA GEMM: C[M,N] = silu(A[M,K] @ W[N,K]^T + bias)
// 256 threads = 4 waves; wave = 16 rows; block M-tile 64; full N sweep per wave.
template<int N, int K>
__global__ __launch_bounds__(256) void k_bgemm(const short* __restrict__ Ah,
    const short* __restrict__ Al, const short* __restrict__ Wh,
    const short* __restrict__ Wl, const float* __restrict__ bias,
    float* __restrict__ Cf, short* __restrict__ Ch, short* __restrict__ Cl){
  constexpr int NT = N/16;
  int lane = threadIdx.x & 63;
  int w = threadIdx.x >> 6;
  int col16 = lane & 15, quad = lane >> 4;
  int m0 = blockIdx.x*64 + w*16;
  int arow = m0 + col16;
  int hoff = quad*8;
  f32x4 acc[NT];
  #pragma unroll
  for (int i=0;i<NT;++i) acc[i] = (f32x4){0.f,0.f,0.f,0.f};
  for (int kc=0; kc<K; kc+=32){
    bf16x8 ah = *(const bf16x8*)(Ah + (size_t)arow*K + kc + hoff);
    bf16x8 al = *(const bf16x8*)(Al + (size_t)arow*K + kc + hoff);
    #pragma unroll
    for (int nt=0; nt<NT; ++nt){
      int n = nt*16 + col16;
      bf16x8 wh = *(const bf16x8*)(Wh + (size_t)n*K + kc + hoff);
      bf16x8 wl = *(const bf16x8*)(Wl + (size_t)n*K + kc + hoff);
      acc[nt] = __builtin_amdgcn_mfma_f32_16x16x32_bf16(ah, wh, acc[nt], 0,0,0);
      acc[nt] = __builtin_amdgcn_mfma_f32_16x16x32_bf16(ah, wl, acc[nt], 0,0,0);
      acc[nt] = __builtin_amdgcn_mfma_f32_16x16x32_bf16(al, wh, acc[nt], 0,0,0);
    }
  }
  #pragma unroll
  for (int nt=0; nt<NT; ++nt){
    int n = nt*16 + col16;
    float bb = bias[n];
    #pragma unroll
    for (int r=0;r<4;++r){
      int m = m0 + quad*4 + r;
      float v = siluf(acc[nt][r] + bb);
      if (Cf) Cf[(size_t)m*N + n] = v;
      if (Ch){
        short hh, ll; split_bf(v, hh, ll);
        Ch[(size_t)m*N + n] = hh;
        Cl[(size_t)m*N + n] = ll;
      }
    }
  }
}

// ---------------- fused mix einsum (MFMA) + nrm scaling + tensor_norm + layernorm(384) -> xh/xl
// block 256 = 4 waves, 16 nodes; wave w covers kout [w*32, w*32+32); g-grouped weights
__global__ __launch_bounds__(256, 4) void k_mix(const short* __restrict__ Pk,
    const short* __restrict__ w0h, const short* __restrict__ w0l,
    const short* __restrict__ w1h, const short* __restrict__ w1l,
    const short* __restrict__ w2h, const short* __restrict__ w2l,
    const float* __restrict__ NRM,
    const float* __restrict__ on_g, const float* __restrict__ on_b,
    short* __restrict__ xh, short* __restrict__ xl){
  __shared__ float xls[16][388];
  int t = threadIdx.x;
  int w = t>>6, lane = t&63;
  int bn = blockIdx.x*16;
  int col16 = lane & 15;
  int quad = lane >> 4;
  int hoff = quad*8;
  int kbase = w*32;
  const short* wgh[3] = {w0h, w1h, w2h};
  const short* wgl[3] = {w0l, w1l, w2l};
  f32x4 acc[10][2];
  #pragma unroll
  for (int p=0;p<10;++p)
    #pragma unroll
    for (int tt=0;tt<2;++tt) acc[p][tt] = (f32x4){0.f,0.f,0.f,0.f};
  const short* Ab0 = Pk + (size_t)blockIdx.x*40960 + (size_t)col16*640 + quad*160;
  #pragma unroll
  for (int hc4=0; hc4<4; ++hc4){
    const short* Abase = Ab0 + hc4*10240;
    int p = 0;
    #pragma unroll
    for (int g=0; g<3; ++g){
      const int gsz = (g==0)?1:((g==1)?3:6);
      bf16x8 bh[2], bl[2];
      #pragma unroll
      for (int tt=0; tt<2; ++tt){
        int row = kbase + tt*16 + col16;
        bh[tt] = *(const bf16x8*)(wgh[g] + row*128 + hc4*32 + hoff);
        bl[tt] = *(const bf16x8*)(wgl[g] + row*128 + hc4*32 + hoff);
      }
      #pragma unroll
      for (int q=0; q<gsz; ++q, ++p){
        bf16x8 ah = *(const bf16x8*)(Abase + p*16);
        bf16x8 al = *(const bf16x8*)(Abase + p*16 + 8);
        #pragma unroll
        for (int tt=0; tt<2; ++tt){
          acc[p][tt] = __builtin_amdgcn_mfma_f32_16x16x32_bf16(ah, bh[tt], acc[p][tt], 0,0,0);
          acc[p][tt] = __builtin_amdgcn_mfma_f32_16x16x32_bf16(ah, bl[tt], acc[p][tt], 0,0,0);
          acc[p][tt] = __builtin_amdgcn_mfma_f32_16x16x32_bf16(al, bh[tt], acc[p][tt], 0,0,0);
        }
      }
    }
  }
  #pragma unroll
  for (int tt=0; tt<2; ++tt){
    int k = kbase + tt*16 + col16;
    #pragma unroll
    for (int r=0; r<4; ++r){
      int nloc = quad*4 + r;
      int n = bn + nloc;
      const float* nr = NRM + (size_t)n*384 + k*3;
      float n0 = nr[0], n1 = nr[1], n2 = nr[2];
      float tI = acc[0][tt][r]*n0;
      float xI = 3.f*tI*tI;
      float a0 = acc[1][tt][r]*n1, a1 = acc[2][tt][r]*n1, a2 = acc[3][tt][r]*n1;
      float xA = 2.f*(a0*a0 + a1*a1 + a2*a2);
      float d0 = acc[4][tt][r]*n2, d1 = acc[5][tt][r]*n2, d2 = acc[6][tt][r]*n2;
      float o0 = acc[7][tt][r]*n2, o1 = acc[8][tt][r]*n2, o2 = acc[9][tt][r]*n2;
      float xS = d0*d0 + d1*d1 + d2*d2 + 2.f*(o0*o0 + o1*o1 + o2*o2);
      xls[nloc][k]       = xI;
      xls[nloc][128 + k] = xA;
      xls[nloc][256 + k] = xS;
    }
  }
  __syncthreads();
  // layernorm over 384, 16 threads per node, thread covers 24 contiguous cols
  int nl = t >> 4, q = t & 15;
  float vv[24];
  float s = 0.f;
  #pragma unroll
  for (int i=0;i<24;++i){ vv[i] = xls[nl][q*24 + i]; s += vv[i]; }
  #pragma unroll
  for (int o=8;o;o>>=1) s += __shfl_xor(s, o, 64);
  float mean = s*(1.0f/384.0f);
  float qsum = 0.f;
  #pragma unroll
  for (int i=0;i<24;++i){ float d = vv[i]-mean; qsum += d*d; }
  #pragma unroll
  for (int o=8;o;o>>=1) qsum += __shfl_xor(qsum, o, 64);
  float rstd = 1.0f/sqrtf(qsum*(1.0f/384.0f) + 1e-5f);
  int n = bn + nl;
  #pragma unroll
  for (int i=0;i<24;++i){
    int c = q*24 + i;
    float val = (vv[i]-mean)*rstd*on_g[c] + on_b[c];
    short hh, ll; split_bf(val, hh, ll);
    xh[(size_t)n*384 + c] = hh;
    xl[(size_t)n*384 + c] = ll;
  }
}

// ---------------- head: silu(X3 @ ol1^T + b1) @ ol2^T + b2 -> y   (wave per node)
__global__ __launch_bounds__(256) void k_head(const float* __restrict__ X3,
    const float* __restrict__ ol1w, const float* __restrict__ ol1b,
    const float* __restrict__ ol2w, const float* __restrict__ ol2b,
    float* __restrict__ y){
  __shared__ float olT[128*64];
  __shared__ float o2[64];
  __shared__ float o1b[64];
  int t = threadIdx.x;
  for (int i=t; i<8192; i+=256){
    int j = i >> 7, ii = i & 127;
    olT[ii*64 + j] = ol1w[i];
  }
  if (t < 64){ o2[t] = ol2w[t]; o1b[t] = ol1b[t]; }
  __syncthreads();
  int wid = t >> 6, l = t & 63;
  float b2 = ol2b[0];
  for (int c=0; c<16; ++c){
    int n = blockIdx.x*64 + c*4 + wid;
    float acc = o1b[l];
    #pragma unroll 8
    for (int i=0;i<128;++i) acc += X3[(size_t)n*128 + i] * olT[i*64 + l];
    float sv = siluf(acc) * o2[l];
    sv = wred64(sv);
    if (l==0) y[n] = sv + b2;
  }
}

extern "C" void kernel_launch(void* const* d_in, const int* in_sizes, int n_in,
                              void* d_out, int out_size, void* d_ws, size_t ws_size,
                              hipStream_t stream) {
  const int*   z      = (const int*)d_in[0];
  const float* pos    = (const float*)d_in[1];
  const int*   ei     = (const int*)d_in[3];   // int64 in reference -> int32 from harness
  const float* emb_w  = (const float*)d_in[4];
  const float* emb2_w = (const float*)d_in[5];
  const float* emb2_b = (const float*)d_in[6];
  const float* dp1_w  = (const float*)d_in[7];
  const float* dp1_b  = (const float*)d_in[8];
  const float* dp2_w  = (const float*)d_in[9];
  const float* dp2_b  = (const float*)d_in[10];
  const float* dp3_w  = (const float*)d_in[11];
  const float* dp3_b  = (const float*)d_in[12];
  const float* lt0_w  = (const float*)d_in[13];
  const float* lt1_w  = (const float*)d_in[14];
  const float* lt2_w  = (const float*)d_in[15];
  const float* ls0_w  = (const float*)d_in[16];
  const float* ls0_b  = (const float*)d_in[17];
  const float* ls1_w  = (const float*)d_in[18];
  const float* ls1_b  = (const float*)d_in[19];
  const float* in_g   = (const float*)d_in[20];
  const float* in_b   = (const float*)d_in[21];
  const float* lin_w  = (const float*)d_in[22];
  const float* lin_b  = (const float*)d_in[23];
  const float* on_g   = (const float*)d_in[24];
  const float* on_b   = (const float*)d_in[25];
  const float* ol1_w  = (const float*)d_in[26];
  const float* ol1_b  = (const float*)d_in[27];
  const float* ol2_w  = (const float*)d_in[28];
  const float* ol2_b  = (const float*)d_in[29];
  float* out = (float*)d_out;

  // scratch: prefer d_ws, fall back to static device pool if too small
  const size_t NEED = 208u*1024u*1024u;
  char* wsb = (char*)d_ws;
  if (ws_size < NEED){
    void* p = nullptr;
    hipGetSymbolAddress(&p, HIP_SYMBOL(g_pool));
    wsb = (char*)p;
  }
  size_t off = 0;
  auto alloc = [&](size_t bytes)->void*{
    void* p = wsb + off;
    off = (off + bytes + 255) & ~(size_t)255;
    return p;
  };
  float* PZ      = (float*)alloc(128*128*4);
  float* QZ      = (float*)alloc(128*128*4);
  int*   counts  = (int*)  alloc(NN*4);
  int*   offsets = (int*)  alloc((NN+1)*4);
  int*   cursor  = (int*)  alloc(NN*4);
  int*   esrc    = (int*)  alloc(NE*4);
  int*   ezs     = (int*)  alloc(NE*4);
  int*   ezd     = (int*)  alloc(NE*4);
  int*   elist   = (int*)  alloc(NE*4);
  float* ev      = (float*)alloc((size_t)NE*4*4);
  short* atth    = (short*)alloc((size_t)NE*32*2);
  short* attl    = (short*)alloc((size_t)NE*32*2);
  short* dwh     = (short*)alloc(3*128*32*2);
  short* dwl     = (short*)alloc(3*128*32*2);
  short* Pk      = (short*)alloc((size_t)NN*128*10*2*2);   // mix-native layout
  short* tnh     = (short*)alloc((size_t)NN*128*2);
  short* tnl     = (short*)alloc((size_t)NN*128*2);
  short* ls0h    = (short*)alloc(256*128*2);
  short* ls0l    = (short*)alloc(256*128*2);
  short* ls1h    = (short*)alloc(384*256*2);
  short* ls1l    = (short*)alloc(384*256*2);
  short* linh    = (short*)alloc(128*384*2);
  short* linl    = (short*)alloc(128*384*2);
  short* lt0h    = (short*)alloc(128*128*2);
  short* lt0l    = (short*)alloc(128*128*2);
  short* lt1h    = (short*)alloc(128*128*2);
  short* lt1l    = (short*)alloc(128*128*2);
  short* lt2h    = (short*)alloc(128*128*2);
  short* lt2l    = (short*)alloc(128*128*2);
  // union region: D1/D2/D3 (phase 1) overlaps T1/NRM/xh/xl/X3 (phase 2)
  size_t ubase = off;
  float* D1      = (float*)alloc((size_t)NE*128*4);
  float* D2      = (float*)alloc((size_t)NE*128*4);
  float* D3      = (float*)alloc((size_t)NE*128*4);
  off = ubase;   // D dead after k_accum2
  short* T1h     = (short*)alloc((size_t)NN*256*2);
  short* T1l     = (short*)alloc((size_t)NN*256*2);
  float* NRM     = (float*)alloc((size_t)NN*384*4);
  short* xh      = (short*)alloc((size_t)NN*384*2);
  short* xl      = (short*)alloc((size_t)NN*384*2);
  float* X3      = (float*)alloc((size_t)NN*128*4);

  hipMemsetAsync(counts, 0, NN*4, stream);

  k_prez<<<128, 128, 0, stream>>>(emb_w, emb2_w, emb2_b, PZ, QZ);
  k_cvtw<<<944, 256, 0, stream>>>(ls0_w, ls1_w, lin_w, lt0_w, lt1_w, lt2_w,
                                  dp1_w, dp2_w, dp3_w,
                                  ls0h, ls0l, ls1h, ls1l, linh, linl,
                                  lt0h, lt0l, lt1h, lt1l, lt2h, lt2l, dwh, dwl);
  k_edge<<<NE/256, 256, 0, stream>>>(ei, pos, z, counts, esrc, ezs, ezd, ev, atth, attl);
  k_scan<<<1, 1024, 0, stream>>>(counts, offsets, cursor);
  k_scatter<<<NE/256, 256, 0, stream>>>(esrc, cursor, elist);
  k_dstage<<<NE/64, 256, 0, stream>>>(offsets, elist, atth, attl, dwh, dwl,
                                      dp1_b, dp2_b, dp3_b, D1, D2, D3);
  k_accum2<<<NN/2, 256, 0, stream>>>(offsets, elist, ezs, ezd, ev, D1, D2, D3,
                                     PZ, QZ, in_g, in_b, Pk, tnh, tnl);
  // nrm = silu(silu(tnorm @ ls0^T + b) @ ls1^T + b)
  k_bgemm<256,128><<<NN/64, 256, 0, stream>>>(tnh, tnl, ls0h, ls0l, ls0_b,
                                              nullptr, T1h, T1l);
  k_bgemm<384,256><<<NN/64, 256, 0, stream>>>(T1h, T1l, ls1h, ls1l, ls1_b,
                                              NRM, nullptr, nullptr);
  k_mix<<<NN/16, 256, 0, stream>>>(Pk, lt0h, lt0l, lt1h, lt1l, lt2h, lt2l,
                                   NRM, on_g, on_b, xh, xl);
  k_bgemm<128,384><<<NN/64, 256, 0, stream>>>(xh, xl, linh, linl, lin_b,
                                              X3, nullptr, nullptr);
  k_head<<<NN/64, 256, 0, stream>>>(X3, ol1_w, ol1_b, ol2_w, ol2_b, out);
}

// Round 6
// 283.067 us; speedup vs baseline: 1.6525x; 1.6525x over previous
//
#include <hip/hip_runtime.h>
#include <math.h>

#define NN 16384
#define NE 65536
#define HH 128

// ---- constants matching the reference exactly (double, folded to f32) ----
constexpr double D_START = 0.011108996538242306;   // exp(-4.5)
constexpr double D_STEP  = (1.0 - D_START) / 31.0;
constexpr float  F_ALPHA = (float)(5.0/4.5);
constexpr double D_BB    = (2.0/32.0)*(1.0 - D_START);
constexpr float  F_BETA  = (float)(1.0/(D_BB*D_BB));
constexpr float  F_PIC   = (float)(M_PI/4.5);

// fallback scratch pool (used if ws_size too small). ~13 MB needed now.
#define POOL_BYTES (32u*1024u*1024u)
__device__ __align__(256) static char g_pool[POOL_BYTES];

typedef __attribute__((ext_vector_type(8))) short bf16x8;
typedef __attribute__((ext_vector_type(4))) float f32x4;

__device__ __forceinline__ float siluf(float x){
  return x * (1.0f/(1.0f + expf(-x)));
}
__device__ __forceinline__ short f2bf(float x){
  unsigned u = __float_as_uint(x);
  unsigned r = (u + 0x7fffu + ((u>>16)&1u)) >> 16;
  return (short)r;
}
__device__ __forceinline__ float bf2f(short h){
  return __uint_as_float(((unsigned)(unsigned short)h)<<16);
}
__device__ __forceinline__ void split_bf(float x, short& h, short& l){
  h = f2bf(x);
  l = f2bf(x - bf2f(h));
}

// ---------------- PZ/QZ precompute: PZ[a][h] = emb_w[a]·emb2_w[h, :128] + b[h]
__global__ __launch_bounds__(128) void k_prez(const float* __restrict__ emb_w,
    const float* __restrict__ emb2_w, const float* __restrict__ emb2_b,
    float* __restrict__ PZ, float* __restrict__ QZ){
  __shared__ float erow[128];
  int a = blockIdx.x, h = threadIdx.x;
  erow[h] = emb_w[a*128 + h];
  __syncthreads();
  float p = 0.f, q = 0.f;
  #pragma unroll 8
  for (int k=0;k<128;++k){
    float e = erow[k];
    p += e * emb2_w[h*256 + k];
    q += e * emb2_w[h*256 + 128 + k];
  }
  PZ[a*128 + h] = p + emb2_b[h];
  QZ[a*128 + h] = q;
}

// ---------------- convert weight matrices to bf16 hi/lo
__global__ __launch_bounds__(256) void k_cvtw(
    const float* __restrict__ ls0, const float* __restrict__ ls1,
    const float* __restrict__ lin, const float* __restrict__ lt0,
    const float* __restrict__ lt1, const float* __restrict__ lt2,
    const float* __restrict__ dp1, const float* __restrict__ dp2,
    const float* __restrict__ dp3, const float* __restrict__ ol1,
    short* __restrict__ ls0h, short* __restrict__ ls0l,
    short* __restrict__ ls1h, short* __restrict__ ls1l,
    short* __restrict__ linh, short* __restrict__ linl,
    short* __restrict__ lt0h, short* __restrict__ lt0l,
    short* __restrict__ lt1h, short* __restrict__ lt1l,
    short* __restrict__ lt2h, short* __restrict__ lt2l,
    short* __restrict__ dwh, short* __restrict__ dwl,
    short* __restrict__ ol1h, short* __restrict__ ol1l){
  int tid = blockIdx.x*256 + threadIdx.x;   // 249856 total
  const float* s; short *dh, *dl; int i;
  if      (tid < 32768)  { s=ls0; dh=ls0h; dl=ls0l; i=tid; }
  else if (tid < 131072) { s=ls1; dh=ls1h; dl=ls1l; i=tid-32768; }
  else if (tid < 180224) { s=lin; dh=linh; dl=linl; i=tid-131072; }
  else if (tid < 196608) { s=lt0; dh=lt0h; dl=lt0l; i=tid-180224; }
  else if (tid < 212992) { s=lt1; dh=lt1h; dl=lt1l; i=tid-196608; }
  else if (tid < 229376) { s=lt2; dh=lt2h; dl=lt2l; i=tid-212992; }
  else if (tid < 241664) {
    int j = tid - 229376;       // 0..12287, [g*4096 + idx]
    int g = j >> 12, idx = j & 4095;
    s = (g==0)?dp1:((g==1)?dp2:dp3);
    short h,l; split_bf(s[idx], h, l);
    dwh[j] = h; dwl[j] = l;
    return;
  }
  else { s=ol1; dh=ol1h; dl=ol1l; i=tid-241664; }
  short h,l; split_bf(s[i], h, l);
  dh[i] = h; dl[i] = l;
}

// ---------------- per-edge: distance, cutoff, RBF(bf16 hi/lo), normalized vec; histogram
__global__ __launch_bounds__(256) void k_edge(const int* __restrict__ ei,
    const float* __restrict__ pos, const int* __restrict__ z,
    int* __restrict__ counts, int* __restrict__ esrc, int* __restrict__ ezs,
    int* __restrict__ ezd, float* __restrict__ ev,
    short* __restrict__ atth, short* __restrict__ attl){
  int e = blockIdx.x*256 + threadIdx.x;
  if (e >= NE) return;
  int s = ei[e];
  int t = ei[NE + e];
  float dx = pos[3*s+0] - pos[3*t+0];
  float dy = pos[3*s+1] - pos[3*t+1];
  float dz = pos[3*s+2] - pos[3*t+2];
  float d = sqrtf(dx*dx + dy*dy + dz*dz);
  if (d < 4.5f){
    atomicAdd(&counts[s], 1);
    esrc[e] = s;
    ezs[e] = z[s];
    ezd[e] = z[t];
    float denom = (s==t) ? 1.0f : d;
    ev[4*e+0] = dx/denom;
    ev[4*e+1] = dy/denom;
    ev[4*e+2] = dz/denom;
    float cut = 0.5f*(cosf(d*F_PIC) + 1.0f);
    ev[4*e+3] = cut;
    float q = expf(-F_ALPHA*d);
    #pragma unroll
    for (int r=0;r<32;++r){
      float m = (float)(D_START + r*D_STEP);
      float u = q - m;
      float a = cut * expf(-F_BETA*u*u);
      short hh, ll; split_bf(a, hh, ll);
      atth[32*e + r] = hh;
      attl[32*e + r] = ll;
    }
  } else {
    esrc[e] = -1;
  }
}

// ---------------- exclusive scan of 16384 counts (single block)
__global__ __launch_bounds__(1024) void k_scan(const int* __restrict__ counts,
    int* __restrict__ offsets, int* __restrict__ cursor){
  __shared__ int part[1024];
  int t = threadIdx.x;
  int loc[16];
  int s = 0;
  #pragma unroll
  for (int i=0;i<16;++i){ loc[i] = counts[t*16+i]; s += loc[i]; }
  part[t] = s;
  __syncthreads();
  for (int o=1;o<1024;o<<=1){
    int add = (t>=o) ? part[t-o] : 0;
    __syncthreads();
    part[t] += add;
    __syncthreads();
  }
  int excl = (t==0) ? 0 : part[t-1];
  #pragma unroll
  for (int i=0;i<16;++i){
    offsets[t*16+i] = excl;
    cursor[t*16+i] = excl;
    excl += loc[i];
  }
  if (t==1023) offsets[NN] = excl;
}

// ---------------- scatter passing edges into CSR order
__global__ __launch_bounds__(256) void k_scatter(const int* __restrict__ esrc,
    int* __restrict__ cursor, int* __restrict__ elist){
  int e = blockIdx.x*256 + threadIdx.x;
  if (e >= NE) return;
  int s = esrc[e];
  if (s < 0) return;
  int p = atomicAdd(&cursor[s], 1);
  elist[p] = e;
}

// =====================================================================
// MEGA: per block of 16 nodes, everything from edge aggregation to y.
// LDS map (78 KB total -> 2 blocks/CU):
//   R1 [0, 25600):     Dt[16][388] f32  ->  tnorm hi/lo (16x160 sh x2)
//                       -> NRM[16][388] f32 -> X3 hi/lo (16x160 sh x2)
//   R2 [25600, 77312): planes frag tiles (20 slots x 16 n x 80 sh = 51200 B)
//                       -> T1 hi/lo (16x288 sh x2) -> xls[16][388] f32
//                       + xh/xl (16x416 sh x2) at offset 25088
//   R3 [77312, 77568): head partials float[4][16]
// =====================================================================
__global__ __launch_bounds__(256, 2) void k_mega(
    const int* __restrict__ offsets, const int* __restrict__ elist,
    const int* __restrict__ ezs, const int* __restrict__ ezd,
    const float* __restrict__ ev,
    const short* __restrict__ atth, const short* __restrict__ attl,
    const short* __restrict__ dwh, const short* __restrict__ dwl,
    const float* __restrict__ db1, const float* __restrict__ db2,
    const float* __restrict__ db3,
    const float* __restrict__ PZ, const float* __restrict__ QZ,
    const float* __restrict__ in_g, const float* __restrict__ in_b,
    const short* __restrict__ w0h, const short* __restrict__ w0l,
    const short* __restrict__ w1h, const short* __restrict__ w1l,
    const short* __restrict__ w2h, const short* __restrict__ w2l,
    const short* __restrict__ ls0h, const short* __restrict__ ls0l,
    const float* __restrict__ ls0b,
    const short* __restrict__ ls1h, const short* __restrict__ ls1l,
    const float* __restrict__ ls1b,
    const short* __restrict__ linh, const short* __restrict__ linl,
    const float* __restrict__ linb,
    const short* __restrict__ ol1h, const short* __restrict__ ol1l,
    const float* __restrict__ ol1b,
    const float* __restrict__ ol2w, const float* __restrict__ ol2b,
    const float* __restrict__ on_g, const float* __restrict__ on_b,
    float* __restrict__ y){
  __shared__ __align__(16) char sm[77568];
  float* Dt   = (float*)(sm);              // [le][388]
  short* tnhL = (short*)(sm);              // [node*160 + h]
  short* tnlL = tnhL + 2560;
  float* NRMt = (float*)(sm);              // [node][388]
  short* X3h  = (short*)(sm);              // [node*160 + h]
  short* X3l  = X3h + 2560;
  short* PlnL = (short*)(sm + 25600);      // [(pl*4+hc4)*1280 + node*80 + quad*16 + hl*8]
  short* T1hL = (short*)(sm + 25600);      // [node*288 + c]
  short* T1lL = T1hL + 4608;
  float* xlsL = (float*)(sm + 25600);      // [node][388]
  short* xhL  = (short*)(sm + 25600 + 25088); // [node*416 + c]
  short* xlL  = xhL + 6656;
  float* partL= (float*)(sm + 77312);      // [w][node]

  int t = threadIdx.x;
  int w = t >> 6, lane = t & 63;
  int col16 = lane & 15, quad = lane >> 4;
  int bn = blockIdx.x*16;
  int node = t >> 4, q = t & 15;

  int e0n = offsets[bn + node], e1n = offsets[bn + node + 1];
  int e0b = offsets[bn], e1b = offsets[bn + 16];

  // ---------------- phase 1: edge chunks (D-stage MFMA + accumulate pv)
  float pv[10][8];
  #pragma unroll
  for (int p=0;p<10;++p)
    #pragma unroll
    for (int i=0;i<8;++i) pv[p][i]=0.f;

  const float* dbp[3] = {db1, db2, db3};
  for (int c0 = e0b; c0 < e1b; c0 += 16){
    // 1a: Dt[le][col] = att[le] . dw[col]^T + bias  (cols split by wave)
    int jA = c0 + col16; if (jA >= e1b) jA = e1b - 1;
    int eA = elist[jA];
    bf16x8 ah = *(const bf16x8*)(atth + (size_t)eA*32 + quad*8);
    bf16x8 al = *(const bf16x8*)(attl + (size_t)eA*32 + quad*8);
    f32x4 dacc[6];
    #pragma unroll
    for (int nt=0;nt<6;++nt) dacc[nt] = (f32x4){0.f,0.f,0.f,0.f};
    #pragma unroll
    for (int nt=0;nt<6;++nt){
      int col = w*96 + nt*16 + col16;
      int g = col >> 7, cg = col & 127;
      bf16x8 wh = *(const bf16x8*)(dwh + g*4096 + cg*32 + quad*8);
      bf16x8 wl = *(const bf16x8*)(dwl + g*4096 + cg*32 + quad*8);
      dacc[nt] = __builtin_amdgcn_mfma_f32_16x16x32_bf16(ah, wh, dacc[nt], 0,0,0);
      dacc[nt] = __builtin_amdgcn_mfma_f32_16x16x32_bf16(ah, wl, dacc[nt], 0,0,0);
      dacc[nt] = __builtin_amdgcn_mfma_f32_16x16x32_bf16(al, wh, dacc[nt], 0,0,0);
    }
    #pragma unroll
    for (int nt=0;nt<6;++nt){
      int col = w*96 + nt*16 + col16;
      int g = col >> 7;
      float bb = dbp[g][col & 127];
      #pragma unroll
      for (int r=0;r<4;++r)
        Dt[(quad*4+r)*388 + col] = dacc[nt][r] + bb;
    }
    __syncthreads();
    // 1b: accumulate this chunk's edges into pv (thread = (node, 8 h))
    int jlo = e0n > c0 ? e0n : c0;
    int jhi0 = c0 + 16; if (jhi0 > e1b) jhi0 = e1b;
    int jhi = e1n < jhi0 ? e1n : jhi0;
    for (int j = jlo; j < jhi; ++j){
      int le = j - c0;
      int e = elist[j];
      float4 evv = *(const float4*)(ev + 4*e);
      int zs = ezs[e], zd = ezd[e];
      const float* pz = PZ + zs*128 + q*8;
      const float* qz = QZ + zd*128 + q*8;
      const float* dr = Dt + le*388 + q*8;
      float vx = evv.x, vy = evv.y, vz = evv.z, cut = evv.w;
      float t3v = (vx*vx + vy*vy + vz*vz)*(1.0f/3.0f);
      #pragma unroll
      for (int i=0;i<8;++i){
        float C = cut * (pz[i] + qz[i]);
        float d1 = dr[i], d2 = dr[128+i], d3 = dr[256+i];
        pv[0][i] += d1*C;
        float wa = d2*C;
        pv[1][i] += wa*vx; pv[2][i] += wa*vy; pv[3][i] += wa*vz;
        float ws = d3*C;
        pv[4][i] += ws*(vx*vx - t3v);
        pv[5][i] += ws*(vy*vy - t3v);
        pv[6][i] += ws*(vz*vz - t3v);
        pv[7][i] += ws*(vx*vy);
        pv[8][i] += ws*(vx*vz);
        pv[9][i] += ws*(vy*vz);
      }
    }
    __syncthreads();
  }

  // ---------------- phase 2: tensor_norm + layernorm(128) -> tnorm tile (R1)
  {
    float tnv[8];
    float s8 = 0.f;
    #pragma unroll
    for (int i=0;i<8;++i){
      float x = 3.f*pv[0][i]*pv[0][i]
              + 2.f*(pv[1][i]*pv[1][i]+pv[2][i]*pv[2][i]+pv[3][i]*pv[3][i])
              + (pv[4][i]*pv[4][i]+pv[5][i]*pv[5][i]+pv[6][i]*pv[6][i])
              + 2.f*(pv[7][i]*pv[7][i]+pv[8][i]*pv[8][i]+pv[9][i]*pv[9][i]);
      tnv[i] = x; s8 += x;
    }
    #pragma unroll
    for (int o=8;o;o>>=1) s8 += __shfl_xor(s8, o, 64);
    float mean = s8*(1.0f/128.0f);
    float vq = 0.f;
    #pragma unroll
    for (int i=0;i<8;++i){ float d = tnv[i]-mean; vq += d*d; }
    #pragma unroll
    for (int o=8;o;o>>=1) vq += __shfl_xor(vq, o, 64);
    float rstd = 1.0f/sqrtf(vq*(1.0f/128.0f) + 1e-5f);
    #pragma unroll
    for (int i=0;i<8;++i){
      int h = q*8 + i;
      float val = (tnv[i]-mean)*rstd*in_g[h] + in_b[h];
      short hh, ll; split_bf(val, hh, ll);
      tnhL[node*160 + h] = hh;
      tnlL[node*160 + h] = ll;
    }
  }

  // ---------------- phase 3/4: mix einsum in two passes of 5 planes (R2)
  const short* wgh[3] = {w0h, w1h, w2h};
  const short* wgl[3] = {w0l, w1l, w2l};
  constexpr int gmap[10] = {0,1,1,1,2,2,2,2,2,2};
  f32x4 acc[10][2];
  #pragma unroll
  for (int pass=0; pass<2; ++pass){
    int pbase = pass*5;
    // write planes pbase..pbase+4 into frag tiles
    #pragma unroll
    for (int pl=0; pl<5; ++pl){
      short* dst = PlnL + (pl*4 + (q>>2))*1280 + node*80 + (q&3)*16;
      #pragma unroll
      for (int i=0;i<8;++i){
        short hh, ll; split_bf(pv[pbase+pl][i], hh, ll);
        dst[i] = hh; dst[8+i] = ll;
      }
    }
    __syncthreads();
    #pragma unroll
    for (int pl=0; pl<5; ++pl)
      #pragma unroll
      for (int tt=0; tt<2; ++tt) acc[pbase+pl][tt] = (f32x4){0.f,0.f,0.f,0.f};
    #pragma unroll
    for (int hc4=0; hc4<4; ++hc4){
      #pragma unroll
      for (int pl=0; pl<5; ++pl){
        int p = pbase + pl;
        const int g = gmap[p];
        bf16x8 bh[2], bl[2];
        #pragma unroll
        for (int tt=0; tt<2; ++tt){
          int row = w*32 + tt*16 + col16;
          bh[tt] = *(const bf16x8*)(wgh[g] + row*128 + hc4*32 + quad*8);
          bl[tt] = *(const bf16x8*)(wgl[g] + row*128 + hc4*32 + quad*8);
        }
        const short* ab = PlnL + (pl*4 + hc4)*1280 + col16*80 + quad*16;
        bf16x8 ah = *(const bf16x8*)(ab);
        bf16x8 al = *(const bf16x8*)(ab + 8);
        #pragma unroll
        for (int tt=0; tt<2; ++tt){
          acc[p][tt] = __builtin_amdgcn_mfma_f32_16x16x32_bf16(ah, bh[tt], acc[p][tt], 0,0,0);
          acc[p][tt] = __builtin_amdgcn_mfma_f32_16x16x32_bf16(ah, bl[tt], acc[p][tt], 0,0,0);
          acc[p][tt] = __builtin_amdgcn_mfma_f32_16x16x32_bf16(al, bh[tt], acc[p][tt], 0,0,0);
        }
      }
    }
    __syncthreads();
  }

  // ---------------- phase 5: nrm MLP (tnorm -> 256 -> 384), NRM -> R1
  {
    // layer 1: N=256, K=128; wave covers 64 cols
    f32x4 macc[4];
    #pragma unroll
    for (int nt=0;nt<4;++nt) macc[nt] = (f32x4){0.f,0.f,0.f,0.f};
    #pragma unroll
    for (int kc=0; kc<4; ++kc){
      bf16x8 tah = *(const bf16x8*)(tnhL + col16*160 + kc*32 + quad*8);
      bf16x8 tal = *(const bf16x8*)(tnlL + col16*160 + kc*32 + quad*8);
      #pragma unroll
      for (int nt=0;nt<4;++nt){
        int n = w*64 + nt*16 + col16;
        bf16x8 wh = *(const bf16x8*)(ls0h + n*128 + kc*32 + quad*8);
        bf16x8 wl = *(const bf16x8*)(ls0l + n*128 + kc*32 + quad*8);
        macc[nt] = __builtin_amdgcn_mfma_f32_16x16x32_bf16(tah, wh, macc[nt], 0,0,0);
        macc[nt] = __builtin_amdgcn_mfma_f32_16x16x32_bf16(tah, wl, macc[nt], 0,0,0);
        macc[nt] = __builtin_amdgcn_mfma_f32_16x16x32_bf16(tal, wh, macc[nt], 0,0,0);
      }
    }
    #pragma unroll
    for (int nt=0;nt<4;++nt){
      int n = w*64 + nt*16 + col16;
      float bb = ls0b[n];
      #pragma unroll
      for (int r=0;r<4;++r){
        float v = siluf(macc[nt][r] + bb);
        short hh, ll; split_bf(v, hh, ll);
        T1hL[(quad*4+r)*288 + n] = hh;
        T1lL[(quad*4+r)*288 + n] = ll;
      }
    }
    __syncthreads();
    // layer 2: N=384, K=256; wave covers 96 cols
    f32x4 nacc[6];
    #pragma unroll
    for (int nt=0;nt<6;++nt) nacc[nt] = (f32x4){0.f,0.f,0.f,0.f};
    #pragma unroll
    for (int kc=0; kc<8; ++kc){
      bf16x8 tah = *(const bf16x8*)(T1hL + col16*288 + kc*32 + quad*8);
      bf16x8 tal = *(const bf16x8*)(T1lL + col16*288 + kc*32 + quad*8);
      #pragma unroll
      for (int nt=0;nt<6;++nt){
        int n = w*96 + nt*16 + col16;
        bf16x8 wh = *(const bf16x8*)(ls1h + n*256 + kc*32 + quad*8);
        bf16x8 wl = *(const bf16x8*)(ls1l + n*256 + kc*32 + quad*8);
        nacc[nt] = __builtin_amdgcn_mfma_f32_16x16x32_bf16(tah, wh, nacc[nt], 0,0,0);
        nacc[nt] = __builtin_amdgcn_mfma_f32_16x16x32_bf16(tah, wl, nacc[nt], 0,0,0);
        nacc[nt] = __builtin_amdgcn_mfma_f32_16x16x32_bf16(tal, wh, nacc[nt], 0,0,0);
      }
    }
    __syncthreads();   // tnorm reads done; safe to overwrite R1 with NRM
    #pragma unroll
    for (int nt=0;nt<6;++nt){
      int n = w*96 + nt*16 + col16;
      float bb = ls1b[n];
      #pragma unroll
      for (int r=0;r<4;++r)
        NRMt[(quad*4+r)*388 + n] = siluf(nacc[nt][r] + bb);
    }
    __syncthreads();
  }

  // ---------------- phase 6: epilogue (scale by nrm, tensor_norm) -> xls (R2)
  #pragma unroll
  for (int tt=0; tt<2; ++tt){
    int k = w*32 + tt*16 + col16;
    #pragma unroll
    for (int r=0; r<4; ++r){
      int nloc = quad*4 + r;
      const float* nr = NRMt + nloc*388 + 3*k;
      float n0 = nr[0], n1 = nr[1], n2 = nr[2];
      float tI = acc[0][tt][r]*n0;
      float xI = 3.f*tI*tI;
      float a0 = acc[1][tt][r]*n1, a1 = acc[2][tt][r]*n1, a2 = acc[3][tt][r]*n1;
      float xA = 2.f*(a0*a0 + a1*a1 + a2*a2);
      float d0 = acc[4][tt][r]*n2, d1 = acc[5][tt][r]*n2, d2 = acc[6][tt][r]*n2;
      float o0 = acc[7][tt][r]*n2, o1 = acc[8][tt][r]*n2, o2 = acc[9][tt][r]*n2;
      float xS = d0*d0 + d1*d1 + d2*d2 + 2.f*(o0*o0 + o1*o1 + o2*o2);
      xlsL[nloc*388 + k]       = xI;
      xlsL[nloc*388 + 128 + k] = xA;
      xlsL[nloc*388 + 256 + k] = xS;
    }
  }
  __syncthreads();

  // ---------------- phase 7: layernorm(384) -> xh/xl (R2 upper)
  {
    float vv[24];
    float s = 0.f;
    #pragma unroll
    for (int i=0;i<24;++i){ vv[i] = xlsL[node*388 + q*24 + i]; s += vv[i]; }
    #pragma unroll
    for (int o=8;o;o>>=1) s += __shfl_xor(s, o, 64);
    float mean = s*(1.0f/384.0f);
    float qsum = 0.f;
    #pragma unroll
    for (int i=0;i<24;++i){ float d = vv[i]-mean; qsum += d*d; }
    #pragma unroll
    for (int o=8;o;o>>=1) qsum += __shfl_xor(qsum, o, 64);
    float rstd = 1.0f/sqrtf(qsum*(1.0f/384.0f) + 1e-5f);
    #pragma unroll
    for (int i=0;i<24;++i){
      int c = q*24 + i;
      float val = (vv[i]-mean)*rstd*on_g[c] + on_b[c];
      short hh, ll; split_bf(val, hh, ll);
      xhL[node*416 + c] = hh;
      xlL[node*416 + c] = ll;
    }
  }
  __syncthreads();

  // ---------------- phase 8: lin GEMM (384 -> 128) + silu -> X3 (R1)
  {
    f32x4 lacc[2];
    #pragma unroll
    for (int nt=0;nt<2;++nt) lacc[nt] = (f32x4){0.f,0.f,0.f,0.f};
    #pragma unroll
    for (int kc=0; kc<12; ++kc){
      bf16x8 xah = *(const bf16x8*)(xhL + col16*416 + kc*32 + quad*8);
      bf16x8 xal = *(const bf16x8*)(xlL + col16*416 + kc*32 + quad*8);
      #pragma unroll
      for (int nt=0;nt<2;++nt){
        int n = w*32 + nt*16 + col16;
        bf16x8 wh = *(const bf16x8*)(linh + n*384 + kc*32 + quad*8);
        bf16x8 wl = *(const bf16x8*)(linl + n*384 + kc*32 + quad*8);
        lacc[nt] = __builtin_amdgcn_mfma_f32_16x16x32_bf16(xah, wh, lacc[nt], 0,0,0);
        lacc[nt] = __builtin_amdgcn_mfma_f32_16x16x32_bf16(xah, wl, lacc[nt], 0,0,0);
        lacc[nt] = __builtin_amdgcn_mfma_f32_16x16x32_bf16(xal, wh, lacc[nt], 0,0,0);
      }
    }
    __syncthreads();   // NRM reads done; safe to overwrite R1 with X3
    #pragma unroll
    for (int nt=0;nt<2;++nt){
      int n = w*32 + nt*16 + col16;
      float bb = linb[n];
      #pragma unroll
      for (int r=0;r<4;++r){
        float v = siluf(lacc[nt][r] + bb);
        short hh, ll; split_bf(v, hh, ll);
        X3h[(quad*4+r)*160 + n] = hh;
        X3l[(quad*4+r)*160 + n] = ll;
      }
    }
    __syncthreads();
  }

  // ---------------- phase 9: head (128 -> 64 -> 1)
  {
    f32x4 hacc = (f32x4){0.f,0.f,0.f,0.f};
    int n = w*16 + col16;
    #pragma unroll
    for (int kc=0; kc<4; ++kc){
      bf16x8 xah = *(const bf16x8*)(X3h + col16*160 + kc*32 + quad*8);
      bf16x8 xal = *(const bf16x8*)(X3l + col16*160 + kc*32 + quad*8);
      bf16x8 wh = *(const bf16x8*)(ol1h + n*128 + kc*32 + quad*8);
      bf16x8 wl = *(const bf16x8*)(ol1l + n*128 + kc*32 + quad*8);
      hacc = __builtin_amdgcn_mfma_f32_16x16x32_bf16(xah, wh, hacc, 0,0,0);
      hacc = __builtin_amdgcn_mfma_f32_16x16x32_bf16(xah, wl, hacc, 0,0,0);
      hacc = __builtin_amdgcn_mfma_f32_16x16x32_bf16(xal, wh, hacc, 0,0,0);
    }
    float b1 = ol1b[n], w2 = ol2w[n];
    #pragma unroll
    for (int r=0;r<4;++r){
      float v = siluf(hacc[r] + b1) * w2;
      #pragma unroll
      for (int o=8;o;o>>=1) v += __shfl_xor(v, o, 64);
      if (col16 == 0) partL[w*16 + quad*4 + r] = v;
    }
    __syncthreads();
    if (t < 16)
      y[bn + t] = partL[t] + partL[16+t] + partL[32+t] + partL[48+t] + ol2b[0];
  }
}

extern "C" void kernel_launch(void* const* d_in, const int* in_sizes, int n_in,
                              void* d_out, int out_size, void* d_ws, size_t ws_size,
                              hipStream_t stream) {
  const int*   z      = (const int*)d_in[0];
  const float* pos    = (const float*)d_in[1];
  const int*   ei     = (const int*)d_in[3];   // int64 in reference -> int32 from harness
  const float* emb_w  = (const float*)d_in[4];
  const float* emb2_w = (const float*)d_in[5];
  const float* emb2_b = (const float*)d_in[6];
  const float* dp1_w  = (const float*)d_in[7];
  const float* dp1_b  = (const float*)d_in[8];
  const float* dp2_w  = (const float*)d_in[9];
  const float* dp2_b  = (const float*)d_in[10];
  const float* dp3_w  = (const float*)d_in[11];
  const float* dp3_b  = (const float*)d_in[12];
  const float* lt0_w  = (const float*)d_in[13];
  const float* lt1_w  = (const float*)d_in[14];
  const float* lt2_w  = (const float*)d_in[15];
  const float* ls0_w  = (const float*)d_in[16];
  const float* ls0_b  = (const float*)d_in[17];
  const float* ls1_w  = (const float*)d_in[18];
  const float* ls1_b  = (const float*)d_in[19];
  const float* in_g   = (const float*)d_in[20];
  const float* in_b   = (const float*)d_in[21];
  const float* lin_w  = (const float*)d_in[22];
  const float* lin_b  = (const float*)d_in[23];
  const float* on_g   = (const float*)d_in[24];
  const float* on_b   = (const float*)d_in[25];
  const float* ol1_w  = (const float*)d_in[26];
  const float* ol1_b  = (const float*)d_in[27];
  const float* ol2_w  = (const float*)d_in[28];
  const float* ol2_b  = (const float*)d_in[29];
  float* out = (float*)d_out;

  const size_t NEED = 16u*1024u*1024u;
  char* wsb = (char*)d_ws;
  if (ws_size < NEED){
    void* p = nullptr;
    hipGetSymbolAddress(&p, HIP_SYMBOL(g_pool));
    wsb = (char*)p;
  }
  size_t off = 0;
  auto alloc = [&](size_t bytes)->void*{
    void* p = wsb + off;
    off = (off + bytes + 255) & ~(size_t)255;
    return p;
  };
  float* PZ      = (float*)alloc(128*128*4);
  float* QZ      = (float*)alloc(128*128*4);
  int*   counts  = (int*)  alloc(NN*4);
  int*   offsets = (int*)  alloc((NN+1)*4);
  int*   cursor  = (int*)  alloc(NN*4);
  int*   esrc    = (int*)  alloc(NE*4);
  int*   ezs     = (int*)  alloc(NE*4);
  int*   ezd     = (int*)  alloc(NE*4);
  int*   elist   = (int*)  alloc(NE*4);
  float* ev      = (float*)alloc((size_t)NE*4*4);
  short* atth    = (short*)alloc((size_t)NE*32*2);
  short* attl    = (short*)alloc((size_t)NE*32*2);
  short* dwh     = (short*)alloc(3*128*32*2);
  short* dwl     = (short*)alloc(3*128*32*2);
  short* ls0h    = (short*)alloc(256*128*2);
  short* ls0l    = (short*)alloc(256*128*2);
  short* ls1h    = (short*)alloc(384*256*2);
  short* ls1l    = (short*)alloc(384*256*2);
  short* linh    = (short*)alloc(128*384*2);
  short* linl    = (short*)alloc(128*384*2);
  short* lt0h    = (short*)alloc(128*128*2);
  short* lt0l    = (short*)alloc(128*128*2);
  short* lt1h    = (short*)alloc(128*128*2);
  short* lt1l    = (short*)alloc(128*128*2);
  short* lt2h    = (short*)alloc(128*128*2);
  short* lt2l    = (short*)alloc(128*128*2);
  short* ol1h    = (short*)alloc(64*128*2);
  short* ol1l    = (short*)alloc(64*128*2);

  hipMemsetAsync(counts, 0, NN*4, stream);

  k_prez<<<128, 128, 0, stream>>>(emb_w, emb2_w, emb2_b, PZ, QZ);
  k_cvtw<<<976, 256, 0, stream>>>(ls0_w, ls1_w, lin_w, lt0_w, lt1_w, lt2_w,
                                  dp1_w, dp2_w, dp3_w, ol1_w,
                                  ls0h, ls0l, ls1h, ls1l, linh, linl,
                                  lt0h, lt0l, lt1h, lt1l, lt2h, lt2l,
                                  dwh, dwl, ol1h, ol1l);
  k_edge<<<NE/256, 256, 0, stream>>>(ei, pos, z, counts, esrc, ezs, ezd, ev, atth, attl);
  k_scan<<<1, 1024, 0, stream>>>(counts, offsets, cursor);
  k_scatter<<<NE/256, 256, 0, stream>>>(esrc, cursor, elist);
  k_mega<<<NN/16, 256, 0, stream>>>(offsets, elist, ezs, ezd, ev, atth, attl,
                                    dwh, dwl, dp1_b, dp2_b, dp3_b,
                                    PZ, QZ, in_g, in_b,
                                    lt0h, lt0l, lt1h, lt1l, lt2h, lt2l,
                                    ls0h, ls0l, ls0_b, ls1h, ls1l, ls1_b,
                                    linh, linl, lin_b, ol1h, ol1l, ol1_b,
                                    ol2_w, ol2_b, on_g, on_b, out);
}